// Round 4
// baseline (151.351 us; speedup 1.0000x reference)
//
#include <hip/hip_runtime.h>

#define BB 4
#define NI 16
#define CC 3
#define HH 256
#define WW 256
#define HWSZ (HH * WW)

// float2 with 4-byte alignment promise: bilinear tap pairs are only
// dword-aligned. Backend emits unaligned-capable dwordx2 (or splits legally).
typedef float f2v __attribute__((ext_vector_type(2)));
typedef f2v f2u __attribute__((aligned(4)));

__device__ __forceinline__ f2v ld2(const float* __restrict__ p) {
    return *reinterpret_cast<const f2u*>(p);
}

// ---------------------------------------------------------------------------
// Per-instance scalars (uniform id -> scalar loads).
// coef = instance_valid * (mode in {0,2,4} ? 1 : mode==3 ? alpha : 0).
// ---------------------------------------------------------------------------
__device__ __forceinline__ float inst_params(
    const float* __restrict__ ml, const float* __restrict__ tp,
    const float* __restrict__ al, const float* __restrict__ iv,
    int id, float th[6]) {
    float best = ml[id * 5];
    int bid = 0;
#pragma unroll
    for (int k = 1; k < 5; ++k) {
        float v = ml[id * 5 + k];
        if (v > best) { best = v; bid = k; }   // strict >: first max, like jnp.argmax
    }
    float coef = (bid == 0 || bid == 2 || bid == 4) ? 1.0f
               : (bid == 3 ? al[id] : 0.0f);
    coef *= iv[id];
#pragma unroll
    for (int k = 0; k < 6; ++k) th[k] = tp[id * 6 + k];
    return coef;
}

// ---------------------------------------------------------------------------
// Pair-based sampler: x1 = x0+1 and y1 = y0+1, so each (row, plane) tap pair
// is one float2 gather based at bx = clamp(x0, 0, W-2). When the clamp shifts
// the base, the x-weights swap columns; OOB weights are already zeroed, so
// the algebra stays exact. Same for the row pair.
// ---------------------------------------------------------------------------
struct Samp {
    int oA, oB;            // row-pair base offsets (column bx)
    float wxA, wxB;        // x weights for columns bx, bx+1
    float wyA, wyB;        // y weights for rows by, by+1 (coef folded in)
};

__device__ __forceinline__ Samp make_samp(const float th[6], float coef, int p) {
    const int h = p >> 8, w = p & (WW - 1);
    const float xs = (2 * w + 1) * (1.0f / WW) - 1.0f;
    const float ys = (2 * h + 1) * (1.0f / HH) - 1.0f;
    const float gx = th[0] * xs + th[1] * ys + th[2];
    const float gy = th[3] * xs + th[4] * ys + th[5];
    const float ix = gx * (0.5f * WW) + (0.5f * WW - 0.5f);
    const float iy = gy * (0.5f * HH) + (0.5f * HH - 0.5f);
    const float x0f = floorf(ix), y0f = floorf(iy);
    const float wx1 = ix - x0f, wy1 = iy - y0f;
    const float wx0 = 1.0f - wx1, wy0 = 1.0f - wy1;
    const int x0 = (int)x0f, y0 = (int)y0f;
    const int x1 = x0 + 1, y1 = y0 + 1;
    // validity-masked weights (zero outside the source image)
    const float wx0v = ((unsigned)x0 < (unsigned)WW) ? wx0 : 0.0f;
    const float wx1v = ((unsigned)x1 < (unsigned)WW) ? wx1 : 0.0f;
    const float wy0v = ((unsigned)y0 < (unsigned)HH) ? (coef * wy0) : 0.0f;
    const float wy1v = ((unsigned)y1 < (unsigned)HH) ? (coef * wy1) : 0.0f;
    // pair bases; weight-swap when the clamp shifted the base
    const int bx = min(max(x0, 0), WW - 2);
    const int by = min(max(y0, 0), HH - 2);
    const bool sx = (x0 != bx);
    const bool sy = (y0 != by);
    Samp s;
    s.wxA = sx ? wx1v : wx0v;  s.wxB = sx ? wx0v : wx1v;
    s.wyA = sy ? wy1v : wy0v;  s.wyB = sy ? wy0v : wy1v;
    s.oA = by * WW + bx;
    s.oB = s.oA + WW;
    return s;
}

__device__ __forceinline__ float bilerp(const float* __restrict__ src, const Samp& s) {
    const f2v a = ld2(src + s.oA);
    const f2v b = ld2(src + s.oB);
    return s.wyA * (s.wxA * a.x + s.wxB * a.y)
         + s.wyB * (s.wxA * b.x + s.wxB * b.y);
}

// ---------------------------------------------------------------------------
// Fused kernel, PLANE-SPLIT for occupancy: the 4 planes (3 g-channels + mask)
// of a pixel share one Samp but are independent, so blockIdx.z splits them
// across two thread-teams:
//   z=0: g-planes 0,1      z=1: g-plane 2 + mask
// This doubles the thread count to 8192 waves = 32 waves/CU (the HW cap) —
// round-3 had 16 waves/CU max (one thread per pixel doing 4 planes serially,
// measured 29% occupancy, latency-bound at 20% HBM). Address math is
// duplicated per team (VALU was 13% busy — free). Traffic unchanged:
// instance sums stay in registers, gpi/mpi written once (nontemporal),
// never re-read.
// ---------------------------------------------------------------------------
__global__ __launch_bounds__(512) void fused_k(
    const float* __restrict__ g0,
    const float* __restrict__ m0,
    const float* __restrict__ ml,
    const float* __restrict__ tp,
    const float* __restrict__ al,
    const float* __restrict__ iv,
    const float* __restrict__ i_bg,
    float* __restrict__ out_gpi,
    float* __restrict__ out_mpi,
    float* __restrict__ out_gmid,
    float* __restrict__ out_mmid,
    float* __restrict__ out_ibase) {
    const int b  = blockIdx.y;                         // 0..3
    const int zz = blockIdx.z;                         // 0: planes {0,1}; 1: {2, mask}
    const int p  = blockIdx.x * 512 + threadIdx.x;     // pixel in [0, HWSZ)

    const size_t offA = zz ? (size_t)(2 * HWSZ) : 0;   // first plane offset in g

    float sA = 0.f, sB = 0.f;

#pragma unroll 2
    for (int ii = 0; ii < NI; ++ii) {
        const int id = b * NI + ii;
        float th[6];
        const float coef = inst_params(ml, tp, al, iv, id, th);

        float vA = 0.f, vB = 0.f;
        if (coef != 0.0f) {                            // block-uniform branch
            const Samp s = make_samp(th, coef, p);
            const float* gsrc = g0 + (size_t)id * CC * HWSZ;
            const float* srcA = gsrc + offA;
            const float* srcB = zz ? (m0 + (size_t)id * HWSZ) : (gsrc + HWSZ);
            vA = bilerp(srcA, s);
            vB = bilerp(srcB, s);
        }

        float* gp = out_gpi + (size_t)id * CC * HWSZ + p;
        float* dstA = gp + offA;
        float* dstB = zz ? (out_mpi + (size_t)id * HWSZ + p) : (gp + HWSZ);
        __builtin_nontemporal_store(vA, dstA);
        __builtin_nontemporal_store(vB, dstB);

        sA += vA; sB += vB;
    }

    const size_t ob = (size_t)b * CC * HWSZ + p;
    if (zz == 0) {
        out_gmid[ob]            = sA;
        out_gmid[ob + HWSZ]     = sB;
        out_ibase[ob]           = sA + i_bg[ob];
        out_ibase[ob + HWSZ]    = sB + i_bg[ob + HWSZ];
    } else {
        out_gmid[ob + 2 * HWSZ]  = sA;
        out_ibase[ob + 2 * HWSZ] = sA + i_bg[ob + 2 * HWSZ];
        out_mmid[(size_t)b * HWSZ + p] = fminf(fmaxf(sB, 0.f), 1.f);
    }
}

extern "C" void kernel_launch(void* const* d_in, const int* in_sizes, int n_in,
                              void* d_out, int out_size, void* d_ws, size_t ws_size,
                              hipStream_t stream) {
    const float* g0          = (const float*)d_in[0];
    const float* m0          = (const float*)d_in[1];
    const float* mode_logits = (const float*)d_in[2];
    const float* tp          = (const float*)d_in[3];
    const float* alpha       = (const float*)d_in[4];
    const float* iv          = (const float*)d_in[5];
    const float* i_bg        = (const float*)d_in[6];

    float* out       = (float*)d_out;
    float* out_gpi   = out;                                        // [B,NI,C,H,W]
    float* out_mpi   = out_gpi  + (size_t)BB * NI * CC * HWSZ;     // [B,NI,1,H,W]
    float* out_gmid  = out_mpi  + (size_t)BB * NI * HWSZ;          // [B,C,H,W]
    float* out_mmid  = out_gmid + (size_t)BB * CC * HWSZ;          // [B,1,H,W]
    float* out_ibase = out_mmid + (size_t)BB * HWSZ;               // [B,C,H,W]

    dim3 grid(HWSZ / 512, BB, 2);                                  // 128 x 4 x 2
    fused_k<<<grid, 512, 0, stream>>>(g0, m0, mode_logits, tp, alpha, iv, i_bg,
                                      out_gpi, out_mpi,
                                      out_gmid, out_mmid, out_ibase);
}